// Round 3
// baseline (102.422 us; speedup 1.0000x reference)
//
#include <hip/hip_runtime.h>
#include <math.h>

#define BATCH 8
#define S 512
#define SS (S * S)          // 262144
#define KMAX 16
#define EMPTY_DD 361.1f     // EMPTY_DIST - distance_thre(=1)
#define SENT 1e9f
#define MAGIC2 0x3C3C3C3C
#define SPIN_MAX (1 << 22)

// ws int layout (NO pre-zeroing: every slot is written before it is read,
// and the only pre-write reads are MAGIC-tagged flag polls):
// [0..256)       cnt1[blk1]   blk1 in [0,256): 32 K1-blocks per image
// [256..4352)    pts[blk1*16 + k]  packed y*512+x (image-local)
// f[4352..5376)  lsum[1024]   per-K2-block partials (blk = img*128 + rg)
// f[5376..6400)  gsum[1024]
// f[6400..7424)  lmax[1024]
// [7424..8448)   flag2[1024] = MAGIC2
#define PTS_OFF  256
#define LSUM_OFF 4352
#define GSUM_OFF 5376
#define LMAX_OFF 6400
#define FLG_OFF  7424

// ---- K1: find highlight points, atomic-free (per-block private slots) ----
__global__ __launch_bounds__(256) void k_points(const float* __restrict__ ptl,
                                                int* __restrict__ wsi) {
    int tid = threadIdx.x;
    int blk = blockIdx.x;        // 256 blocks: 32 per image, 16 rows each
    int b  = blk >> 5;
    int rg = blk & 31;

    __shared__ int l_cnt;
    __shared__ int l_fnd[KMAX];
    if (tid == 0) l_cnt = 0;
    __syncthreads();

    const float4* p4 = (const float4*)(ptl + b * SS + rg * (16 * S));
#pragma unroll
    for (int q = 0; q < 8; q++) {
        float4 v = p4[q * 256 + tid];            // lane-consecutive float4
        if (v.x + v.y + v.z + v.w != 0.0f) {     // labels are >= 0
            int i0 = rg * (16 * S) + (q * 256 + tid) * 4;
            float c[4] = {v.x, v.y, v.z, v.w};
#pragma unroll
            for (int j = 0; j < 4; j++) {
                if (c[j] != 0.0f) {
                    int slot = atomicAdd(&l_cnt, 1);   // shared-mem atomic only
                    if (slot < KMAX) l_fnd[slot] = i0 + j;
                }
            }
        }
    }
    __syncthreads();
    int lcnt = l_cnt; if (lcnt > KMAX) lcnt = KMAX;
    if (tid == 0) wsi[blk] = lcnt;
    if (tid < lcnt) wsi[PTS_OFF + blk * KMAX + tid] = l_fnd[tid];
}

// ---- K2: gather points + fused Sobel + distance + final reduction ----
__global__ __launch_bounds__(256, 4) void k_main(const float* __restrict__ pred,
                                                 const float* __restrict__ ori,
                                                 int* __restrict__ wsi,
                                                 float* __restrict__ wsf,
                                                 float* __restrict__ out) {
    int tid = threadIdx.x;
    int blk = blockIdx.x;        // 1024 blocks: 128 per image, 4 rows each
    int b  = blk >> 7;
    int rg = blk & 127;
    int wave = tid >> 6;         // 0..3, one row per wave
    int lane = tid & 63;

    __shared__ int l_list[KMAX];
    __shared__ int l_total;
    __shared__ float sm[4][3];
    __shared__ float fin[8][3];

    // ---- gather this image's points from the 32 K1-block lists (wave 0) ----
    if (wave == 0) {
        int cj = 0;
        if (lane < 32) cj = wsi[(b << 5) + lane];
        int pre = cj;
#pragma unroll
        for (int d = 1; d < 32; d <<= 1) {
            int t = __shfl_up(pre, d, 64);
            if (lane >= d && lane < 32) pre += t;
        }
        if (lane == 31) l_total = (pre > KMAX) ? KMAX : pre;
        int off = pre - cj;      // exclusive prefix
        if (lane < 32) {
            for (int k = 0; k < cj; k++) {
                if (off + k < KMAX)
                    l_list[off + k] = wsi[PTS_OFF + ((b << 5) + lane) * KMAX + k];
            }
        }
    }
    __syncthreads();

    int cnt = l_total;
    bool has = cnt > 0;
    float pyk[KMAX], pxk[KMAX];
#pragma unroll
    for (int k = 0; k < KMAX; k++) {
        if (k < cnt) {
            int pk = l_list[k];
            pyk[k] = (float)(pk >> 9);
            pxk[k] = (float)(pk & 511);
        } else { pyk[k] = SENT; pxk[k] = SENT; }
    }

    const float* pb = pred + b * SS;
    const float* ob = ori + b * SS;
    int y = rg * 4 + wave;       // wave-uniform row
    int x0 = lane << 3;

    const float4* prow = (const float4*)(pb + y * S + x0);
    float4 pA = prow[0], pB = prow[1];

    // ---- Sobel for own row ----
    float gsum = 0.0f;
    if (y > 0 && y < S - 1) {
        float r[3][10];
#pragma unroll
        for (int ri = 0; ri < 3; ri++) {
            int yy = y - 1 + ri;
            const float4* pr  = (const float4*)(pb + yy * S + x0);
            const float4* orr = (const float4*)(ob + yy * S + x0);
            float4 p0 = (ri == 1) ? pA : pr[0];
            float4 p1 = (ri == 1) ? pB : pr[1];
            float4 o0 = orr[0], o1 = orr[1];
            r[ri][1] = p0.x * o0.x; r[ri][2] = p0.y * o0.y;
            r[ri][3] = p0.z * o0.z; r[ri][4] = p0.w * o0.w;
            r[ri][5] = p1.x * o1.x; r[ri][6] = p1.y * o1.y;
            r[ri][7] = p1.z * o1.z; r[ri][8] = p1.w * o1.w;
            r[ri][0] = __shfl_up(r[ri][8], 1, 64);    // lane0 value dead (x=0 zeroed)
            r[ri][9] = __shfl_down(r[ri][1], 1, 64);  // lane63 value dead (x=511 zeroed)
        }
#pragma unroll
        for (int j = 0; j < 8; j++) {
            float a00 = r[0][j], a01 = r[0][j + 1], a02 = r[0][j + 2];
            float a10 = r[1][j],                    a12 = r[1][j + 2];
            float a20 = r[2][j], a21 = r[2][j + 1], a22 = r[2][j + 2];
            float g0 = -a00 + a02 - 2.0f * a10 + 2.0f * a12 - a20 + a22;
            float g1 =  a00 + 2.0f * a01 + a02 - a20 - 2.0f * a21 - a22;
            float g2 =  2.0f * a00 + a01 + a10 - a12 - a21 - 2.0f * a22;
            float g3 =  a01 + 2.0f * a02 - a10 + a12 - 2.0f * a20 - a21;
            float gv = fmaxf(fmaxf(fabsf(g0), fabsf(g1)), fmaxf(fabsf(g2), fabsf(g3)));
            bool edge = (lane == 0 && j == 0) || (lane == 63 && j == 7);
            gsum += edge ? 0.0f : gv;
        }
    }

    // ---- distance for own row ----
    float fy = (float)y;
    float fx = (float)x0;
    float m[8];
#pragma unroll
    for (int j = 0; j < 8; j++) m[j] = 1e30f;
#pragma unroll
    for (int k = 0; k < KMAX; k++) {
        float dy = fy - pyk[k];
        float dy2 = dy * dy;
        float dx = fx - pxk[k];
#pragma unroll
        for (int j = 0; j < 8; j++) {
            float d = dx + (float)j;
            m[j] = fminf(m[j], fmaf(d, d, dy2));
        }
    }
    float dd[8];
#pragma unroll
    for (int j = 0; j < 8; j++)
        dd[j] = has ? fmaxf(sqrtf(m[j]) - 1.0f, 0.0f) : EMPTY_DD;

    float lsum = pA.x * dd[0] + pA.y * dd[1] + pA.z * dd[2] + pA.w * dd[3] +
                 pB.x * dd[4] + pB.y * dd[5] + pB.z * dd[6] + pB.w * dd[7];
    float lmax = fmaxf(fmaxf(fmaxf(dd[0], dd[1]), fmaxf(dd[2], dd[3])),
                       fmaxf(fmaxf(dd[4], dd[5]), fmaxf(dd[6], dd[7])));

    // ---- block reduce (4 waves) + publish partials with release flag ----
#pragma unroll
    for (int off = 32; off > 0; off >>= 1) {
        lsum += __shfl_down(lsum, off, 64);
        gsum += __shfl_down(gsum, off, 64);
        lmax = fmaxf(lmax, __shfl_down(lmax, off, 64));
    }
    if (lane == 0) { sm[wave][0] = lsum; sm[wave][1] = gsum; sm[wave][2] = lmax; }
    __syncthreads();
    if (tid == 0) {
#pragma unroll
        for (int w = 1; w < 4; w++) {
            lsum += sm[w][0];
            gsum += sm[w][1];
            lmax = fmaxf(lmax, sm[w][2]);
        }
        wsf[LSUM_OFF + blk] = lsum;
        wsf[GSUM_OFF + blk] = gsum;
        wsf[LMAX_OFF + blk] = lmax;
        __threadfence();
        __hip_atomic_store(&wsi[FLG_OFF + blk], MAGIC2,
                           __ATOMIC_RELEASE, __HIP_MEMORY_SCOPE_AGENT);
    }

    // ---- block 0 only: spin (writers never wait -> deadlock-free), finalize ----
    if (blk == 0) {
        int i0 = tid << 2;       // 4 flags per thread
        bool ok = false;
        for (int g = 0; g < SPIN_MAX; g++) {
            if (!ok) {
                int v0 = __hip_atomic_load(&wsi[FLG_OFF + i0 + 0], __ATOMIC_RELAXED, __HIP_MEMORY_SCOPE_AGENT);
                int v1 = __hip_atomic_load(&wsi[FLG_OFF + i0 + 1], __ATOMIC_RELAXED, __HIP_MEMORY_SCOPE_AGENT);
                int v2 = __hip_atomic_load(&wsi[FLG_OFF + i0 + 2], __ATOMIC_RELAXED, __HIP_MEMORY_SCOPE_AGENT);
                int v3 = __hip_atomic_load(&wsi[FLG_OFF + i0 + 3], __ATOMIC_RELAXED, __HIP_MEMORY_SCOPE_AGENT);
                ok = (v0 == MAGIC2) && (v1 == MAGIC2) && (v2 == MAGIC2) && (v3 == MAGIC2);
            }
            if (__syncthreads_and(ok)) break;
        }
        __threadfence();
        // 4 consecutive partials per thread; all 4 belong to image (tid>>5)
        float ls = 0.0f, gs = 0.0f, lm = 0.0f;
#pragma unroll
        for (int i = 0; i < 4; i++) {
            ls += __hip_atomic_load(&wsf[LSUM_OFF + i0 + i], __ATOMIC_RELAXED, __HIP_MEMORY_SCOPE_AGENT);
            gs += __hip_atomic_load(&wsf[GSUM_OFF + i0 + i], __ATOMIC_RELAXED, __HIP_MEMORY_SCOPE_AGENT);
            lm = fmaxf(lm, __hip_atomic_load(&wsf[LMAX_OFF + i0 + i], __ATOMIC_RELAXED, __HIP_MEMORY_SCOPE_AGENT));
        }
        // segment-reduce 32-lane groups (one image per group of 32 tids)
#pragma unroll
        for (int off = 16; off > 0; off >>= 1) {
            ls += __shfl_down(ls, off, 32);
            gs += __shfl_down(gs, off, 32);
            lm = fmaxf(lm, __shfl_down(lm, off, 32));
        }
        if ((lane & 31) == 0) {
            int img = (wave << 1) | (lane >> 5);
            fin[img][0] = ls; fin[img][1] = gs; fin[img][2] = lm;
        }
        __syncthreads();
        if (tid == 0) {
            float dl = 0.0f, gl = 0.0f;
#pragma unroll
            for (int bb = 0; bb < BATCH; bb++) {
                dl += fin[bb][0] / fin[bb][2];
                gl += fin[bb][1];
            }
            out[0] = dl / (float)(SS * BATCH);
            out[1] = gl / (float)(SS * BATCH);
        }
    }
}

extern "C" void kernel_launch(void* const* d_in, const int* in_sizes, int n_in,
                              void* d_out, int out_size, void* d_ws, size_t ws_size,
                              hipStream_t stream) {
    const float* pred = (const float*)d_in[0];
    const float* ptl  = (const float*)d_in[1];
    const float* ori  = (const float*)d_in[2];
    float* out = (float*)d_out;
    int* wsi = (int*)d_ws;
    float* wsf = (float*)d_ws;

    k_points<<<256, 256, 0, stream>>>(ptl, wsi);
    k_main<<<1024, 256, 0, stream>>>(pred, ori, wsi, wsf, out);
}

// Round 4
// 79.830 us; speedup vs baseline: 1.2830x; 1.2830x over previous
//
#include <hip/hip_runtime.h>
#include <math.h>

#define BATCH 8
#define S 512
#define SS (S * S)          // 262144
#define KMAX 16
#define EMPTY_DD 361.1f     // EMPTY_DIST - distance_thre(=1)
#define SENT 1e9f

// ws int layout (NO pre-zeroing needed: every slot is written by an earlier
// kernel before any later kernel reads it; kernel boundaries give visibility):
// [0..256)       cnt1[blk1]   blk1 in [0,256): 32 K1-blocks per image
// [256..4352)    pts[blk1*16 + k]  packed y*512+x (image-local)
// f[4352..5376)  lsum[1024]   per-K2-block partials (blk = img*128 + rg)
// f[5376..6400)  gsum[1024]
// f[6400..7424)  lmax[1024]
#define PTS_OFF  256
#define LSUM_OFF 4352
#define GSUM_OFF 5376
#define LMAX_OFF 6400

// ---- K1: find highlight points, atomic-free (per-block private slots) ----
__global__ __launch_bounds__(256) void k_points(const float* __restrict__ ptl,
                                                int* __restrict__ wsi) {
    int tid = threadIdx.x;
    int blk = blockIdx.x;        // 256 blocks: 32 per image, 16 rows each
    int b  = blk >> 5;
    int rg = blk & 31;

    __shared__ int l_cnt;
    __shared__ int l_fnd[KMAX];
    if (tid == 0) l_cnt = 0;
    __syncthreads();

    const float4* p4 = (const float4*)(ptl + b * SS + rg * (16 * S));
#pragma unroll
    for (int q = 0; q < 8; q++) {
        float4 v = p4[q * 256 + tid];            // lane-consecutive float4
        if (v.x + v.y + v.z + v.w != 0.0f) {     // labels are >= 0
            int i0 = rg * (16 * S) + (q * 256 + tid) * 4;
            float c[4] = {v.x, v.y, v.z, v.w};
#pragma unroll
            for (int j = 0; j < 4; j++) {
                if (c[j] != 0.0f) {
                    int slot = atomicAdd(&l_cnt, 1);   // shared-mem atomic only
                    if (slot < KMAX) l_fnd[slot] = i0 + j;
                }
            }
        }
    }
    __syncthreads();
    int lcnt = l_cnt; if (lcnt > KMAX) lcnt = KMAX;
    if (tid == 0) wsi[blk] = lcnt;
    if (tid < lcnt) wsi[PTS_OFF + blk * KMAX + tid] = l_fnd[tid];
}

// ---- K2: gather points + fused Sobel + distance, partials per block ----
__global__ __launch_bounds__(256, 4) void k_main(const float* __restrict__ pred,
                                                 const float* __restrict__ ori,
                                                 const int* __restrict__ wsi,
                                                 float* __restrict__ wsf) {
    int tid = threadIdx.x;
    int blk = blockIdx.x;        // 1024 blocks: 128 per image, 4 rows each
    int b  = blk >> 7;
    int rg = blk & 127;
    int wave = tid >> 6;         // 0..3, one row per wave
    int lane = tid & 63;

    __shared__ int l_list[KMAX];
    __shared__ int l_total;
    __shared__ float sm[4][3];

    // ---- gather this image's points from the 32 K1-block lists (wave 0) ----
    if (wave == 0) {
        int cj = 0;
        if (lane < 32) cj = wsi[(b << 5) + lane];
        int pre = cj;
#pragma unroll
        for (int d = 1; d < 32; d <<= 1) {
            int t = __shfl_up(pre, d, 64);
            if (lane >= d && lane < 32) pre += t;
        }
        if (lane == 31) l_total = (pre > KMAX) ? KMAX : pre;
        int off = pre - cj;      // exclusive prefix
        if (lane < 32) {
            for (int k = 0; k < cj; k++) {
                if (off + k < KMAX)
                    l_list[off + k] = wsi[PTS_OFF + ((b << 5) + lane) * KMAX + k];
            }
        }
    }
    __syncthreads();

    int cnt = l_total;
    bool has = cnt > 0;
    float pyk[KMAX], pxk[KMAX];
#pragma unroll
    for (int k = 0; k < KMAX; k++) {
        if (k < cnt) {
            int pk = l_list[k];
            pyk[k] = (float)(pk >> 9);
            pxk[k] = (float)(pk & 511);
        } else { pyk[k] = SENT; pxk[k] = SENT; }
    }

    const float* pb = pred + b * SS;
    const float* ob = ori + b * SS;
    int y = rg * 4 + wave;       // wave-uniform row
    int x0 = lane << 3;

    const float4* prow = (const float4*)(pb + y * S + x0);
    float4 pA = prow[0], pB = prow[1];

    // ---- Sobel for own row ----
    float gsum = 0.0f;
    if (y > 0 && y < S - 1) {
        float r[3][10];
#pragma unroll
        for (int ri = 0; ri < 3; ri++) {
            int yy = y - 1 + ri;
            const float4* pr  = (const float4*)(pb + yy * S + x0);
            const float4* orr = (const float4*)(ob + yy * S + x0);
            float4 p0 = (ri == 1) ? pA : pr[0];
            float4 p1 = (ri == 1) ? pB : pr[1];
            float4 o0 = orr[0], o1 = orr[1];
            r[ri][1] = p0.x * o0.x; r[ri][2] = p0.y * o0.y;
            r[ri][3] = p0.z * o0.z; r[ri][4] = p0.w * o0.w;
            r[ri][5] = p1.x * o1.x; r[ri][6] = p1.y * o1.y;
            r[ri][7] = p1.z * o1.z; r[ri][8] = p1.w * o1.w;
            r[ri][0] = __shfl_up(r[ri][8], 1, 64);    // lane0 value dead (x=0 zeroed)
            r[ri][9] = __shfl_down(r[ri][1], 1, 64);  // lane63 value dead (x=511 zeroed)
        }
#pragma unroll
        for (int j = 0; j < 8; j++) {
            float a00 = r[0][j], a01 = r[0][j + 1], a02 = r[0][j + 2];
            float a10 = r[1][j],                    a12 = r[1][j + 2];
            float a20 = r[2][j], a21 = r[2][j + 1], a22 = r[2][j + 2];
            float g0 = -a00 + a02 - 2.0f * a10 + 2.0f * a12 - a20 + a22;
            float g1 =  a00 + 2.0f * a01 + a02 - a20 - 2.0f * a21 - a22;
            float g2 =  2.0f * a00 + a01 + a10 - a12 - a21 - 2.0f * a22;
            float g3 =  a01 + 2.0f * a02 - a10 + a12 - 2.0f * a20 - a21;
            float gv = fmaxf(fmaxf(fabsf(g0), fabsf(g1)), fmaxf(fabsf(g2), fabsf(g3)));
            bool edge = (lane == 0 && j == 0) || (lane == 63 && j == 7);
            gsum += edge ? 0.0f : gv;
        }
    }

    // ---- distance for own row ----
    float fy = (float)y;
    float fx = (float)x0;
    float m[8];
#pragma unroll
    for (int j = 0; j < 8; j++) m[j] = 1e30f;
#pragma unroll
    for (int k = 0; k < KMAX; k++) {
        float dy = fy - pyk[k];
        float dy2 = dy * dy;
        float dx = fx - pxk[k];
#pragma unroll
        for (int j = 0; j < 8; j++) {
            float d = dx + (float)j;
            m[j] = fminf(m[j], fmaf(d, d, dy2));
        }
    }
    float dd[8];
#pragma unroll
    for (int j = 0; j < 8; j++)
        dd[j] = has ? fmaxf(sqrtf(m[j]) - 1.0f, 0.0f) : EMPTY_DD;

    float lsum = pA.x * dd[0] + pA.y * dd[1] + pA.z * dd[2] + pA.w * dd[3] +
                 pB.x * dd[4] + pB.y * dd[5] + pB.z * dd[6] + pB.w * dd[7];
    float lmax = fmaxf(fmaxf(fmaxf(dd[0], dd[1]), fmaxf(dd[2], dd[3])),
                       fmaxf(fmaxf(dd[4], dd[5]), fmaxf(dd[6], dd[7])));

    // ---- block reduce (4 waves) + publish partials (plain stores) ----
#pragma unroll
    for (int off = 32; off > 0; off >>= 1) {
        lsum += __shfl_down(lsum, off, 64);
        gsum += __shfl_down(gsum, off, 64);
        lmax = fmaxf(lmax, __shfl_down(lmax, off, 64));
    }
    if (lane == 0) { sm[wave][0] = lsum; sm[wave][1] = gsum; sm[wave][2] = lmax; }
    __syncthreads();
    if (tid == 0) {
#pragma unroll
        for (int w = 1; w < 4; w++) {
            lsum += sm[w][0];
            gsum += sm[w][1];
            lmax = fmaxf(lmax, sm[w][2]);
        }
        wsf[LSUM_OFF + blk] = lsum;
        wsf[GSUM_OFF + blk] = gsum;
        wsf[LMAX_OFF + blk] = lmax;
    }
}

// ---- K3: final reduction over 1024 partials ----
__global__ __launch_bounds__(1024) void k_final(const float* __restrict__ wsf,
                                                float* __restrict__ out) {
    int tid = threadIdx.x;
    int lane = tid & 63;
    int w = tid >> 6;            // 0..15; image = w>>1 (partials laid out [img][128])

    __shared__ float smf[16][3];

    float ls = wsf[LSUM_OFF + tid];
    float gs = wsf[GSUM_OFF + tid];
    float lm = wsf[LMAX_OFF + tid];
#pragma unroll
    for (int off = 32; off > 0; off >>= 1) {
        ls += __shfl_down(ls, off, 64);
        gs += __shfl_down(gs, off, 64);
        lm = fmaxf(lm, __shfl_down(lm, off, 64));
    }
    if (lane == 0) { smf[w][0] = ls; smf[w][1] = gs; smf[w][2] = lm; }
    __syncthreads();
    if (tid == 0) {
        float dl = 0.0f, gl = 0.0f;
#pragma unroll
        for (int img = 0; img < BATCH; img++) {
            float l = smf[2 * img][0] + smf[2 * img + 1][0];
            float g = smf[2 * img][1] + smf[2 * img + 1][1];
            float mx = fmaxf(smf[2 * img][2], smf[2 * img + 1][2]);
            dl += l / mx;
            gl += g;
        }
        out[0] = dl / (float)(SS * BATCH);
        out[1] = gl / (float)(SS * BATCH);
    }
}

extern "C" void kernel_launch(void* const* d_in, const int* in_sizes, int n_in,
                              void* d_out, int out_size, void* d_ws, size_t ws_size,
                              hipStream_t stream) {
    const float* pred = (const float*)d_in[0];
    const float* ptl  = (const float*)d_in[1];
    const float* ori  = (const float*)d_in[2];
    float* out = (float*)d_out;
    int* wsi = (int*)d_ws;
    float* wsf = (float*)d_ws;

    k_points<<<256, 256, 0, stream>>>(ptl, wsi);
    k_main<<<1024, 256, 0, stream>>>(pred, ori, wsi, wsf);
    k_final<<<1, 1024, 0, stream>>>(wsf, out);
}